// Round 7
// baseline (495.032 us; speedup 1.0000x reference)
//
#include <hip/hip_runtime.h>

#define BB 1024
#define TB 512
#define FB 64
#define NH1 32
#define NH2 16
#define ND1 16
#define ND2 8

// Wavefront-scope fence: runtime-free compiler barrier against LDS motion
// across masked-publish -> read handoffs (single-wave blocks: HW is in-order,
// only compiler reordering needs suppressing).
#define WAVE_FENCE() __builtin_amdgcn_fence(__ATOMIC_ACQ_REL, "wavefront")

__device__ __forceinline__ float tanh_fast(float v) {
    // tanh(x) = 1 - 2/(e^{2x}+1); exp inf/0 limits give exactly +-1.
    float e = __expf(2.0f * v);
    return fmaf(-2.0f, __builtin_amdgcn_rcpf(e + 1.0f), 1.0f);
}

// ============================================================================
// Kernel A: XP[b][t][h] = x[b][t][:] @ Wx1[:][h] + b1[h]   (fully parallel)
// grid (1024, 4) x 256 threads. thread = (h = tid&31, tslot = tid>>5).
// Each thread: full 64-dot for 16 timesteps (t = qd*128 + k*8 + tslot).
// Weights held in 64 registers (static-indexed unrolled loops -> no scratch).
// x read as float4 (same addr across the 32 lanes of a tslot -> broadcast
// fetch); stores coalesced in 128B groups. HBM-bound (~192 MB total).
// ============================================================================
__global__ __attribute__((amdgpu_flat_work_group_size(256, 256)))
void xp_gemm_kernel(const float* __restrict__ x, const float* __restrict__ Wx1,
                    const float* __restrict__ b1, float* __restrict__ xp)
{
    const int b  = blockIdx.x;
    const int qd = blockIdx.y;           // quarter of T
    const int h  = threadIdx.x & 31;     // output unit
    const int ts = threadIdx.x >> 5;     // timestep slot 0..7

    float wc[FB];
#pragma unroll
    for (int f = 0; f < FB; ++f) wc[f] = Wx1[f * NH1 + h];
    const float bb = b1[h];

    const float* xr  = x  + (size_t)b * TB * FB  + (size_t)(qd * 128) * FB;
    float*       xpo = xp + (size_t)b * TB * NH1 + (size_t)(qd * 128) * NH1;

#pragma unroll 4
    for (int k = 0; k < 16; ++k) {
        const int tl = k * 8 + ts;
        const float4* xv = (const float4*)(xr + (size_t)tl * FB);
        float a0 = bb, a1 = 0.0f, a2 = 0.0f, a3 = 0.0f;
#pragma unroll
        for (int j = 0; j < 16; ++j) {
            float4 v = xv[j];
            a0 = fmaf(v.x, wc[4 * j + 0], a0);
            a1 = fmaf(v.y, wc[4 * j + 1], a1);
            a2 = fmaf(v.z, wc[4 * j + 2], a2);
            a3 = fmaf(v.w, wc[4 * j + 3], a3);
        }
        xpo[(size_t)tl * NH1 + h] = (a0 + a1) + (a2 + a3);
    }
}

// ============================================================================
// Kernel B: the recurrence. One wave per batch element (R0's proven
// structure) with the xp computation DELETED: xp comes from the workspace
// via one prefetched global dword per 2 steps (XP[b][t..t+1][*] is 64
// contiguous floats = one perfectly coalesced wave load; lane (h,p) holds
// XP[t+p][h]). xp is added in exactly one half (parity select) before the
// cross-half shfl reduce. Per step: 4 b128 h1 reads + 16 FMA + shfl + tanh
// + L2 (2 b128 + 1 b128 + 12 FMA + 2 shfl + tanh) + 2 masked writes.
// ============================================================================
__global__ __attribute__((amdgpu_flat_work_group_size(64, 64)))
           __attribute__((amdgpu_waves_per_eu(1, 1)))
void rnn_seq_kernel(
    const float* __restrict__ xp,   // [B][T][NH1], b1 already folded in
    const float* __restrict__ Wh1,
    const float* __restrict__ Wx2, const float* __restrict__ Wh2, const float* __restrict__ b2,
    const float* __restrict__ W3,  const float* __restrict__ b3,
    const float* __restrict__ W4,  const float* __restrict__ b4,
    const float* __restrict__ Wo,  const float* __restrict__ bo,
    float* __restrict__ out)
{
    __shared__ __align__(16) float h1s[NH1];
    __shared__ __align__(16) float h2s[NH2];
    __shared__ __align__(16) float ys[ND1];

    const int lane = threadIdx.x;
    const int h = lane & 31;
    const int p = lane >> 5;
    const int g = lane & 15;
    const int q = lane >> 4;
    const int b = blockIdx.x;

    auto r1 = [&](int i) { return Wh1[(16 * p + i) * NH1 + h]; };
    const float4 wha = make_float4(r1(0),  r1(1),  r1(2),  r1(3));
    const float4 whb = make_float4(r1(4),  r1(5),  r1(6),  r1(7));
    const float4 whc = make_float4(r1(8),  r1(9),  r1(10), r1(11));
    const float4 whd = make_float4(r1(12), r1(13), r1(14), r1(15));
    auto w2 = [&](int i) { return Wx2[(8 * q + i) * NH2 + g]; };
    const float4 x2a = make_float4(w2(0), w2(1), w2(2), w2(3));
    const float4 x2b = make_float4(w2(4), w2(5), w2(6), w2(7));
    auto r2 = [&](int i) { return Wh2[(4 * q + i) * NH2 + g]; };
    const float4 h2w = make_float4(r2(0), r2(1), r2(2), r2(3));
    const float b2v = (q == 0) ? b2[g] : 0.0f;  // added once after quarter-combine

    if (lane < NH1) h1s[lane] = 0.0f;
    if (lane < NH2) h2s[lane] = 0.0f;
    __syncthreads();

    // xp prefetch: one dword per 2 steps; 4-deep queue = 8 steps of cover.
    const float* xpb = xp + (size_t)b * TB * NH1 + lane;
    float xq0 = xpb[0 * NH1];
    float xq1 = xpb[2 * NH1];
    float xq2 = xpb[4 * NH1];
    float xq3 = xpb[6 * NH1];

// One timestep. PAR = t&1 (compile-time): the half of the wave whose queue
// register holds XP[t][h] adds it pre-reduce (xp enters the sum exactly once).
#define SSTEP(T_E, PAR, XQ)                                                    \
    {                                                                          \
        WAVE_FENCE();                                                          \
        const int t_ = (T_E);                                                  \
        float4 hva = *(const float4*)&h1s[16 * p + 0];                         \
        float4 hvb = *(const float4*)&h1s[16 * p + 4];                         \
        float4 hvc = *(const float4*)&h1s[16 * p + 8];                         \
        float4 hvd = *(const float4*)&h1s[16 * p + 12];                        \
        float a0 = (p == (PAR)) ? (XQ) : 0.0f;                                 \
        float a1 = 0.0f, a2 = 0.0f, a3 = 0.0f;                                 \
        a0 = fmaf(hva.x, wha.x, a0); a1 = fmaf(hva.y, wha.y, a1);              \
        a2 = fmaf(hva.z, wha.z, a2); a3 = fmaf(hva.w, wha.w, a3);              \
        a0 = fmaf(hvb.x, whb.x, a0); a1 = fmaf(hvb.y, whb.y, a1);              \
        a2 = fmaf(hvb.z, whb.z, a2); a3 = fmaf(hvb.w, whb.w, a3);              \
        a0 = fmaf(hvc.x, whc.x, a0); a1 = fmaf(hvc.y, whc.y, a1);              \
        a2 = fmaf(hvc.z, whc.z, a2); a3 = fmaf(hvc.w, whc.w, a3);              \
        a0 = fmaf(hvd.x, whd.x, a0); a1 = fmaf(hvd.y, whd.y, a1);              \
        a2 = fmaf(hvd.z, whd.z, a2); a3 = fmaf(hvd.w, whd.w, a3);              \
        float acc = (a0 + a1) + (a2 + a3);                                     \
        acc += __shfl_xor(acc, 32, 64);                                        \
        float h1new = tanh_fast(acc);                                          \
        if (t_ > 0) {  /* layer 2, one step behind: h2_{t-1} from h1_{t-1} */  \
            float4 u0 = *(const float4*)&h1s[8 * q + 0];                       \
            float4 u1 = *(const float4*)&h1s[8 * q + 4];                       \
            float4 hw = *(const float4*)&h2s[4 * q];                           \
            float c0 = b2v, c1 = 0.0f;                                         \
            c0 = fmaf(u0.x, x2a.x, c0); c1 = fmaf(u0.y, x2a.y, c1);            \
            c0 = fmaf(u0.z, x2a.z, c0); c1 = fmaf(u0.w, x2a.w, c1);            \
            c0 = fmaf(u1.x, x2b.x, c0); c1 = fmaf(u1.y, x2b.y, c1);            \
            c0 = fmaf(u1.z, x2b.z, c0); c1 = fmaf(u1.w, x2b.w, c1);            \
            c0 = fmaf(hw.x, h2w.x, c0); c1 = fmaf(hw.y, h2w.y, c1);            \
            c0 = fmaf(hw.z, h2w.z, c0); c1 = fmaf(hw.w, h2w.w, c1);            \
            float cc = c0 + c1;                                                \
            cc += __shfl_xor(cc, 16, 64);                                      \
            cc += __shfl_xor(cc, 32, 64);                                      \
            float h2new = tanh_fast(cc);                                       \
            if (lane < NH2) h2s[lane] = h2new;                                 \
        }                                                                      \
        WAVE_FENCE(); /* no h1s read below this point in the iteration */      \
        if (p == 0) h1s[h] = h1new;                                            \
    }

    for (int tb = 0; tb < TB; tb += 8) {
        // refill loads for t = tb+8 .. tb+15 (clamped; extras never consumed)
        int n0 = tb + 8;  n0 = (n0 <= TB - 2) ? n0 : (TB - 2);
        int n1 = tb + 10; n1 = (n1 <= TB - 2) ? n1 : (TB - 2);
        int n2 = tb + 12; n2 = (n2 <= TB - 2) ? n2 : (TB - 2);
        int n3 = tb + 14; n3 = (n3 <= TB - 2) ? n3 : (TB - 2);
        float xn0 = xpb[(size_t)n0 * NH1];
        float xn1 = xpb[(size_t)n1 * NH1];
        float xn2 = xpb[(size_t)n2 * NH1];
        float xn3 = xpb[(size_t)n3 * NH1];
        SSTEP(tb + 0, 0, xq0) SSTEP(tb + 1, 1, xq0)
        SSTEP(tb + 2, 0, xq1) SSTEP(tb + 3, 1, xq1)
        SSTEP(tb + 4, 0, xq2) SSTEP(tb + 5, 1, xq2)
        SSTEP(tb + 6, 0, xq3) SSTEP(tb + 7, 1, xq3)
        xq0 = xn0; xq1 = xn1; xq2 = xn2; xq3 = xn3;
    }
#undef SSTEP

    WAVE_FENCE();

    // ---- epilogue: layer 2 for t = T-1 ----
    {
        float4 u0 = *(const float4*)&h1s[8 * q + 0];
        float4 u1 = *(const float4*)&h1s[8 * q + 4];
        float4 hw = *(const float4*)&h2s[4 * q];
        float c0 = b2v, c1 = 0.0f;
        c0 = fmaf(u0.x, x2a.x, c0); c1 = fmaf(u0.y, x2a.y, c1);
        c0 = fmaf(u0.z, x2a.z, c0); c1 = fmaf(u0.w, x2a.w, c1);
        c0 = fmaf(u1.x, x2b.x, c0); c1 = fmaf(u1.y, x2b.y, c1);
        c0 = fmaf(u1.z, x2b.z, c0); c1 = fmaf(u1.w, x2b.w, c1);
        c0 = fmaf(hw.x, h2w.x, c0); c1 = fmaf(hw.y, h2w.y, c1);
        c0 = fmaf(hw.z, h2w.z, c0); c1 = fmaf(hw.w, h2w.w, c1);
        float cc = c0 + c1;
        cc += __shfl_xor(cc, 16, 64);
        cc += __shfl_xor(cc, 32, 64);
        float h2fin = tanh_fast(cc);
        WAVE_FENCE();
        if (lane < NH2) h2s[lane] = h2fin;
        WAVE_FENCE();
    }

    // ---- dense head (scalar form, known good) ----
    float a3h = b3[g];
#pragma unroll
    for (int j = 0; j < 16; ++j) a3h = fmaf(h2s[j], W3[j * ND1 + g], a3h);
    float y1 = fmaxf(a3h, 0.0f);
    WAVE_FENCE();
    if (lane < ND1) ys[lane] = y1;
    WAVE_FENCE();

    const int e = lane & 7;
    float a4 = b4[e];
#pragma unroll
    for (int j = 0; j < 16; ++j) a4 = fmaf(ys[j], W4[j * ND2 + e], a4);

    float yo = a4 * Wo[e];
    yo += __shfl_xor(yo, 1, 64);
    yo += __shfl_xor(yo, 2, 64);
    yo += __shfl_xor(yo, 4, 64);
    if (lane == 0) out[b] = yo + bo[0];
}

// ============================================================================
// Fallback: the R0 baseline kernel (215 us, verified) — used only when the
// workspace is too small for XP.
// ============================================================================
__global__ __attribute__((amdgpu_flat_work_group_size(64, 64)))
           __attribute__((amdgpu_waves_per_eu(1, 1)))
void rnn_fallback_kernel(
    const float* __restrict__ x,
    const float* __restrict__ Wx1, const float* __restrict__ Wh1, const float* __restrict__ b1,
    const float* __restrict__ Wx2, const float* __restrict__ Wh2, const float* __restrict__ b2,
    const float* __restrict__ W3,  const float* __restrict__ b3,
    const float* __restrict__ W4,  const float* __restrict__ b4,
    const float* __restrict__ Wo,  const float* __restrict__ bo,
    float* __restrict__ out)
{
    __shared__ __align__(16) float xs[2][FB];
    __shared__ __align__(16) float h1s[NH1];
    __shared__ __align__(16) float h2s[NH2];
    __shared__ __align__(16) float ys[ND1];

    const int lane = threadIdx.x;
    const int h = lane & 31;
    const int p = lane >> 5;
    const int g = lane & 15;
    const int q = lane >> 4;
    const int b = blockIdx.x;

    auto w1 = [&](int i) { return Wx1[(32 * p + i) * NH1 + h]; };
    auto r1 = [&](int i) { return Wh1[(16 * p + i) * NH1 + h]; };
    auto w2 = [&](int i) { return Wx2[(8 * q + i) * NH2 + g]; };
    auto r2 = [&](int i) { return Wh2[(4 * q + i) * NH2 + g]; };
    const float4 wxa = make_float4(w1(0),  w1(1),  w1(2),  w1(3));
    const float4 wxb = make_float4(w1(4),  w1(5),  w1(6),  w1(7));
    const float4 wxc = make_float4(w1(8),  w1(9),  w1(10), w1(11));
    const float4 wxd = make_float4(w1(12), w1(13), w1(14), w1(15));
    const float4 wxe = make_float4(w1(16), w1(17), w1(18), w1(19));
    const float4 wxf = make_float4(w1(20), w1(21), w1(22), w1(23));
    const float4 wxg = make_float4(w1(24), w1(25), w1(26), w1(27));
    const float4 wxh = make_float4(w1(28), w1(29), w1(30), w1(31));
    const float4 wha = make_float4(r1(0),  r1(1),  r1(2),  r1(3));
    const float4 whb = make_float4(r1(4),  r1(5),  r1(6),  r1(7));
    const float4 whc = make_float4(r1(8),  r1(9),  r1(10), r1(11));
    const float4 whd = make_float4(r1(12), r1(13), r1(14), r1(15));
    const float4 x2a = make_float4(w2(0), w2(1), w2(2), w2(3));
    const float4 x2b = make_float4(w2(4), w2(5), w2(6), w2(7));
    const float4 h2w = make_float4(r2(0), r2(1), r2(2), r2(3));
    const float b1v = (p == 0) ? b1[h] : 0.0f;
    const float b2v = (q == 0) ? b2[g] : 0.0f;

    if (lane < NH1) h1s[lane] = 0.0f;
    if (lane < NH2) h2s[lane] = 0.0f;

    const float* xb = x + (size_t)b * TB * FB + lane;
    float xq0 = xb[0 * FB];
    float xq1 = xb[1 * FB];
    float xq2 = xb[2 * FB];
    float xq3 = xb[3 * FB];
    xs[0][lane] = xq0;
    __syncthreads();

#define FSTEP(T, SLOT, QSTAGE, QREFILL)                                        \
    {                                                                          \
        WAVE_FENCE();                                                          \
        const int t_ = (T);                                                    \
        int tn_ = t_ + 4; tn_ = (tn_ < TB) ? tn_ : (TB - 1);                   \
        const float xnew_ = xb[tn_ * FB];                                      \
        xs[(SLOT) ^ 1][lane] = QSTAGE;                                         \
        float4 hva = *(const float4*)&h1s[16 * p + 0];                         \
        float4 hvb = *(const float4*)&h1s[16 * p + 4];                         \
        float4 hvc = *(const float4*)&h1s[16 * p + 8];                         \
        float4 hvd = *(const float4*)&h1s[16 * p + 12];                        \
        const float4* xv = (const float4*)&xs[SLOT][32 * p];                   \
        float a0 = b1v, a1 = 0.0f, a2 = 0.0f, a3 = 0.0f;                       \
        float4 v_;                                                             \
        v_ = xv[0]; a0 = fmaf(v_.x, wxa.x, a0); a1 = fmaf(v_.y, wxa.y, a1);    \
                    a2 = fmaf(v_.z, wxa.z, a2); a3 = fmaf(v_.w, wxa.w, a3);    \
        v_ = xv[1]; a0 = fmaf(v_.x, wxb.x, a0); a1 = fmaf(v_.y, wxb.y, a1);    \
                    a2 = fmaf(v_.z, wxb.z, a2); a3 = fmaf(v_.w, wxb.w, a3);    \
        v_ = xv[2]; a0 = fmaf(v_.x, wxc.x, a0); a1 = fmaf(v_.y, wxc.y, a1);    \
                    a2 = fmaf(v_.z, wxc.z, a2); a3 = fmaf(v_.w, wxc.w, a3);    \
        v_ = xv[3]; a0 = fmaf(v_.x, wxd.x, a0); a1 = fmaf(v_.y, wxd.y, a1);    \
                    a2 = fmaf(v_.z, wxd.z, a2); a3 = fmaf(v_.w, wxd.w, a3);    \
        v_ = xv[4]; a0 = fmaf(v_.x, wxe.x, a0); a1 = fmaf(v_.y, wxe.y, a1);    \
                    a2 = fmaf(v_.z, wxe.z, a2); a3 = fmaf(v_.w, wxe.w, a3);    \
        v_ = xv[5]; a0 = fmaf(v_.x, wxf.x, a0); a1 = fmaf(v_.y, wxf.y, a1);    \
                    a2 = fmaf(v_.z, wxf.z, a2); a3 = fmaf(v_.w, wxf.w, a3);    \
        v_ = xv[6]; a0 = fmaf(v_.x, wxg.x, a0); a1 = fmaf(v_.y, wxg.y, a1);    \
                    a2 = fmaf(v_.z, wxg.z, a2); a3 = fmaf(v_.w, wxg.w, a3);    \
        v_ = xv[7]; a0 = fmaf(v_.x, wxh.x, a0); a1 = fmaf(v_.y, wxh.y, a1);    \
                    a2 = fmaf(v_.z, wxh.z, a2); a3 = fmaf(v_.w, wxh.w, a3);    \
        a0 = fmaf(hva.x, wha.x, a0); a1 = fmaf(hva.y, wha.y, a1);              \
        a2 = fmaf(hva.z, wha.z, a2); a3 = fmaf(hva.w, wha.w, a3);              \
        a0 = fmaf(hvb.x, whb.x, a0); a1 = fmaf(hvb.y, whb.y, a1);              \
        a2 = fmaf(hvb.z, whb.z, a2); a3 = fmaf(hvb.w, whb.w, a3);              \
        a0 = fmaf(hvc.x, whc.x, a0); a1 = fmaf(hvc.y, whc.y, a1);              \
        a2 = fmaf(hvc.z, whc.z, a2); a3 = fmaf(hvc.w, whc.w, a3);              \
        a0 = fmaf(hvd.x, whd.x, a0); a1 = fmaf(hvd.y, whd.y, a1);              \
        a2 = fmaf(hvd.z, whd.z, a2); a3 = fmaf(hvd.w, whd.w, a3);              \
        float acc = (a0 + a1) + (a2 + a3);                                     \
        acc += __shfl_xor(acc, 32, 64);                                        \
        float h1new = tanh_fast(acc);                                          \
        if (t_ > 0) {                                                          \
            float4 u0 = *(const float4*)&h1s[8 * q + 0];                       \
            float4 u1 = *(const float4*)&h1s[8 * q + 4];                       \
            float4 hw = *(const float4*)&h2s[4 * q];                           \
            float c0 = b2v, c1 = 0.0f;                                         \
            c0 = fmaf(u0.x, x2a.x, c0); c1 = fmaf(u0.y, x2a.y, c1);            \
            c0 = fmaf(u0.z, x2a.z, c0); c1 = fmaf(u0.w, x2a.w, c1);            \
            c0 = fmaf(u1.x, x2b.x, c0); c1 = fmaf(u1.y, x2b.y, c1);            \
            c0 = fmaf(u1.z, x2b.z, c0); c1 = fmaf(u1.w, x2b.w, c1);            \
            c0 = fmaf(hw.x, h2w.x, c0); c1 = fmaf(hw.y, h2w.y, c1);            \
            c0 = fmaf(hw.z, h2w.z, c0); c1 = fmaf(hw.w, h2w.w, c1);            \
            float cc = c0 + c1;                                                \
            cc += __shfl_xor(cc, 16, 64);                                      \
            cc += __shfl_xor(cc, 32, 64);                                      \
            float h2new = tanh_fast(cc);                                       \
            if (lane < NH2) h2s[lane] = h2new;                                 \
        }                                                                      \
        WAVE_FENCE();                                                          \
        if (p == 0) h1s[h] = h1new;                                            \
        QREFILL = xnew_;                                                       \
    }

    for (int tb = 0; tb < TB; tb += 4) {
        FSTEP(tb + 0, 0, xq1, xq0);
        FSTEP(tb + 1, 1, xq2, xq1);
        FSTEP(tb + 2, 0, xq3, xq2);
        FSTEP(tb + 3, 1, xq0, xq3);
    }
#undef FSTEP

    WAVE_FENCE();
    {
        float4 u0 = *(const float4*)&h1s[8 * q + 0];
        float4 u1 = *(const float4*)&h1s[8 * q + 4];
        float4 hw = *(const float4*)&h2s[4 * q];
        float c0 = b2v, c1 = 0.0f;
        c0 = fmaf(u0.x, x2a.x, c0); c1 = fmaf(u0.y, x2a.y, c1);
        c0 = fmaf(u0.z, x2a.z, c0); c1 = fmaf(u0.w, x2a.w, c1);
        c0 = fmaf(u1.x, x2b.x, c0); c1 = fmaf(u1.y, x2b.y, c1);
        c0 = fmaf(u1.z, x2b.z, c0); c1 = fmaf(u1.w, x2b.w, c1);
        c0 = fmaf(hw.x, h2w.x, c0); c1 = fmaf(hw.y, h2w.y, c1);
        c0 = fmaf(hw.z, h2w.z, c0); c1 = fmaf(hw.w, h2w.w, c1);
        float cc = c0 + c1;
        cc += __shfl_xor(cc, 16, 64);
        cc += __shfl_xor(cc, 32, 64);
        float h2fin = tanh_fast(cc);
        WAVE_FENCE();
        if (lane < NH2) h2s[lane] = h2fin;
        WAVE_FENCE();
    }

    float a3h = b3[g];
#pragma unroll
    for (int j = 0; j < 16; ++j) a3h = fmaf(h2s[j], W3[j * ND1 + g], a3h);
    float y1 = fmaxf(a3h, 0.0f);
    WAVE_FENCE();
    if (lane < ND1) ys[lane] = y1;
    WAVE_FENCE();

    const int e = lane & 7;
    float a4 = b4[e];
#pragma unroll
    for (int j = 0; j < 16; ++j) a4 = fmaf(ys[j], W4[j * ND2 + e], a4);

    float yo = a4 * Wo[e];
    yo += __shfl_xor(yo, 1, 64);
    yo += __shfl_xor(yo, 2, 64);
    yo += __shfl_xor(yo, 4, 64);
    if (lane == 0) out[b] = yo + bo[0];
}

extern "C" void kernel_launch(void* const* d_in, const int* in_sizes, int n_in,
                              void* d_out, int out_size, void* d_ws, size_t ws_size,
                              hipStream_t stream) {
    const float* x   = (const float*)d_in[0];
    const float* Wx1 = (const float*)d_in[1];
    const float* Wh1 = (const float*)d_in[2];
    const float* b1  = (const float*)d_in[3];
    const float* Wx2 = (const float*)d_in[4];
    const float* Wh2 = (const float*)d_in[5];
    const float* b2  = (const float*)d_in[6];
    const float* W3  = (const float*)d_in[7];
    const float* b3  = (const float*)d_in[8];
    const float* W4  = (const float*)d_in[9];
    const float* b4  = (const float*)d_in[10];
    const float* Wo  = (const float*)d_in[11];
    const float* bo  = (const float*)d_in[12];
    float* out = (float*)d_out;

    const size_t need = (size_t)BB * TB * NH1 * sizeof(float);   // 64 MB
    if (d_ws != nullptr && ws_size >= need) {
        float* xpw = (float*)d_ws;
        xp_gemm_kernel<<<dim3(BB, 4), dim3(256), 0, stream>>>(x, Wx1, b1, xpw);
        rnn_seq_kernel<<<dim3(BB), dim3(64), 0, stream>>>(
            xpw, Wh1, Wx2, Wh2, b2, W3, b3, W4, b4, Wo, bo, out);
    } else {
        rnn_fallback_kernel<<<dim3(BB), dim3(64), 0, stream>>>(
            x, Wx1, Wh1, b1, Wx2, Wh2, b2, W3, b3, W4, b4, Wo, bo, out);
    }
}